// Round 4
// baseline (506.729 us; speedup 1.0000x reference)
//
#include <hip/hip_runtime.h>
#include <math.h>
#include <stdint.h>

typedef unsigned long long u64;
typedef unsigned int u32;

#define NCLS 80
#define NA   8400
#define NB   16
#define PRE_K 1000

// ---------------- ws layout (bytes) ----------------
// f_keys : u64   [NB][NA]      @ 0         (1,075,200)
// boxes  : float4[NB][NA]      @ 1,075,200 (2,150,400)
// labels : int   [NB][NA]      @ 3,225,600 (  537,600)
// cand   : u64   [NB][1024]    @ 3,763,200 (  131,072)
// mask   : u64   [NB][1000][16]@ 3,894,272 (2,048,000)
// diag   : u64   [NB][1024]    @ 5,942,272 (  131,072)  row i word (i>>6), self-bit cleared
// total ~6.07 MB

__device__ inline u64 shfl64(u64 v, int src) {
    unsigned lo = (unsigned)__shfl((int)(u32)v, src, 64);
    unsigned hi = (unsigned)__shfl((int)(u32)(v >> 32), src, 64);
    return ((u64)hi << 32) | (u64)lo;
}

// ------------------------------------------------------------------
// Kernel 1: per-anchor max/argmax over 80 classes, sigmoid score,
// box decode, sort-key emit.  (unchanged)
// ------------------------------------------------------------------
__global__ __launch_bounds__(256) void k_decode(
    const float* __restrict__ cls0, const float* __restrict__ cls1,
    const float* __restrict__ cls2, const float* __restrict__ box0,
    const float* __restrict__ box1, const float* __restrict__ box2,
    u64* __restrict__ f_keys, float4* __restrict__ boxes,
    int* __restrict__ labels)
{
    int a = blockIdx.x * blockDim.x + threadIdx.x;
    int b = blockIdx.y;
    if (a >= NA) return;

    const float* clsp; const float* boxp;
    int Wd, s, hw, HW;
    if (a < 6400)      { clsp = cls0; boxp = box0; Wd = 80; s = 8;  hw = a;        HW = 6400; }
    else if (a < 8000) { clsp = cls1; boxp = box1; Wd = 40; s = 16; hw = a - 6400; HW = 1600; }
    else               { clsp = cls2; boxp = box2; Wd = 20; s = 32; hw = a - 8000; HW = 400;  }

    const float* cp = clsp + (size_t)b * NCLS * HW + hw;
    float m = cp[0];
    int lab = 0;
#pragma unroll 8
    for (int c = 1; c < NCLS; ++c) {
        float v = cp[(size_t)c * HW];
        if (v > m) { m = v; lab = c; }   // strict > keeps first index on ties
    }
    double e = exp(-(double)m);
    float sc = (float)(1.0 / (1.0 + e));
    float sz = (sc > 0.25f) ? sc : 0.0f;
    f_keys[(size_t)b * NA + a] = ((u64)__float_as_uint(sz) << 32) | (u64)(~(u32)a);

    const float* bp = boxp + (size_t)b * 4 * HW + hw;
    float fs = (float)s;
    float d0 = bp[0] * fs, d1 = bp[HW] * fs, d2 = bp[2 * HW] * fs, d3 = bp[3 * HW] * fs;
    float px = (float)((hw % Wd) * s);
    float py = (float)((hw / Wd) * s);
    boxes[(size_t)b * NA + a] = make_float4(px - d0, py - d1, px + d2, py + d3);
    labels[(size_t)b * NA + a] = lab;
}

// ------------------------------------------------------------------
// Kernel 2: exact top-1000 via histogram selection + bitonic-2048.
// Fallback: original full bitonic-8192 path (correct for any input).
// R3 est: full sort ~91 LDS phases x 4 CAS/thread; new: 66 x 1.
// ------------------------------------------------------------------
__global__ __launch_bounds__(1024) void k_sort(
    const u64* __restrict__ f_keys, u64* __restrict__ cand)
{
    __shared__ u64 sh[8192];            // 64 KB; fast path aliases regions
    u32* H    = (u32*)sh;               // 4096 bins   -> sh[0..2047]
    u32* CS   = (u32*)(sh + 2048);      // 1024 sums   -> sh[2048..2559]
    u64* BUF  = sh + 4096;              // 2048 keys   -> sh[4096..6143]
    u32* MISC = (u32*)(sh + 6144);      // [0]=total [1]=B [2]=C [3]=cnt

    int b = blockIdx.x, tid = threadIdx.x, lane = tid & 63;
    const u64* fk = f_keys + (size_t)b * NA;
    u64* cb = cand + (size_t)b * 1024;

    for (int i = tid; i < 4096; i += 1024) H[i] = 0;
    if (tid == 0) { MISC[0] = 0; MISC[1] = 0; MISC[2] = 0xFFFFFFFFu; MISC[3] = 0; }
    __syncthreads();

    // histogram on score bits: score in (0.25,1) -> bin (sb>>12)-0x3E800 in [0,4095]
    for (int i = tid; i < NA; i += 1024) {
        u32 sb = (u32)(fk[i] >> 32);
        if (sb) {
            int bin = (int)(sb >> 12) - 0x3E800;
            bin = max(0, min(bin, 4095));
            atomicAdd(&H[bin], 1u);
        }
    }
    __syncthreads();

    CS[tid] = H[4*tid] + H[4*tid+1] + H[4*tid+2] + H[4*tid+3];
    __syncthreads();

    if (tid < 64) {
        u32 g = 0;
        for (int j = 0; j < 16; ++j) g += CS[lane*16 + j];
        u32 S = g;
        for (int off = 1; off < 64; off <<= 1) {
            u32 x = __shfl_down(S, off, 64);
            if (lane + off < 64) S += x;          // suffix sum over lane chunks
        }
        if (lane == 0) MISC[0] = S;
        u32 Snext = S - g;
        if (S >= PRE_K && Snext < PRE_K) {        // unique crossing lane
            u32 accAbove = Snext;
            int tB = lane * 16;
            for (int j = 15; j >= 0; --j) {
                u32 c4 = CS[lane*16 + j];
                if (accAbove + c4 >= PRE_K) { tB = lane*16 + j; break; }
                accAbove += c4;
            }
            int B = 4 * tB; u32 Cv = 0;
            for (int k2 = 3; k2 >= 0; --k2) {
                u32 hc = H[4*tB + k2];
                if (accAbove + hc >= PRE_K) { B = 4*tB + k2; Cv = accAbove + hc; break; }
                accAbove += hc;
            }
            MISC[1] = (u32)B; MISC[2] = Cv;
        }
    }
    __syncthreads();
    u32 total = MISC[0], Bb = MISC[1], Cv = MISC[2];
    bool fb = (total < PRE_K) || (Cv > 2048);     // block-uniform

    if (!fb) {
        // compact survivors (order-independent; sort canonicalizes)
        for (int i = tid; i < NA; i += 1024) {
            u64 key = fk[i];
            u32 sb = (u32)(key >> 32);
            if (sb) {
                int bin = (int)(sb >> 12) - 0x3E800;
                bin = max(0, min(bin, 4095));
                if ((u32)bin >= Bb) {
                    u32 p = atomicAdd(&MISC[3], 1u);
                    BUF[p] = key;
                }
            }
        }
        __syncthreads();
        for (int i = tid; i < 2048; i += 1024) if (i >= (int)Cv) BUF[i] = 0ull;
        __syncthreads();
        // descending bitonic over 2048, 1 CAS/thread/phase
        for (int k = 2; k <= 2048; k <<= 1) {
            for (int j = k >> 1; j > 0; j >>= 1) {
                int i = ((tid & ~(j-1)) << 1) | (tid & (j-1));
                int l = i | j;
                u64 x = BUF[i], y = BUF[l];
                bool sw = ((i & k) == 0) ? (x < y) : (x > y);
                if (sw) { BUF[i] = y; BUF[l] = x; }
                __syncthreads();
            }
        }
        if (tid < PRE_K) cb[tid] = BUF[tid];
    } else {
        // -------- fallback: original exact full sort --------
        __syncthreads();
        for (int i = tid; i < 8192; i += 1024) sh[i] = fk[i];
        __syncthreads();
        for (int k = 2; k <= 8192; k <<= 1) {
            for (int j = k >> 1; j > 0; j >>= 1) {
                for (int t = tid; t < 4096; t += 1024) {
                    int i = ((t & ~(j - 1)) << 1) | (t & (j - 1));
                    int l = i | j;
                    u64 x = sh[i], y = sh[l];
                    bool sw = ((i & k) == 0) ? (x < y) : (x > y);
                    if (sw) { sh[i] = y; sh[l] = x; }
                }
                __syncthreads();
            }
        }
        if (tid < 256) sh[7936 + tid] = (tid < 208) ? fk[8192 + tid] : 0ull;
        __syncthreads();
        for (int k = 2; k <= 256; k <<= 1) {
            for (int j = k >> 1; j > 0; j >>= 1) {
                for (int t = tid; t < 128; t += 1024) {
                    int i = ((t & ~(j - 1)) << 1) | (t & (j - 1));
                    int l = i | j;
                    u64 x = sh[7936 + i], y = sh[7936 + l];
                    bool sw = ((i & k) == 0) ? (x < y) : (x > y);
                    if (sw) { sh[7936 + i] = y; sh[7936 + l] = x; }
                }
                __syncthreads();
            }
        }
        if (tid < 1000) {
            u64 x = sh[tid];
            int lo = 0, hi = 256;
            while (lo < hi) { int mid = (lo + hi) >> 1; if (sh[7936 + mid] > x) lo = mid + 1; else hi = mid; }
            int r = tid + lo;
            if (r < PRE_K) cb[r] = x;
        }
        if (tid < 256) {
            u64 x = sh[7936 + tid];
            int lo = 0, hi = 1024;
            while (lo < hi) { int mid = (lo + hi) >> 1; if (sh[mid] > x) lo = mid + 1; else hi = mid; }
            int r = tid + lo;
            if (r < PRE_K) cb[r] = x;
        }
    }
}

// ------------------------------------------------------------------
// Kernel 3: IoU bitmask matrix + diag array (row i word i>>6, self-bit
// CLEARED — k_nms's cur update then needs no andn).
// ------------------------------------------------------------------
__global__ __launch_bounds__(1024) void k_iou(
    const u64* __restrict__ cand, const float4* __restrict__ boxes,
    const int* __restrict__ labels, u64* __restrict__ mask,
    u64* __restrict__ diag)
{
    __shared__ float sx1[1000], sy1[1000], sx2[1000], sy2[1000], sar[1000];
    int b = blockIdx.y, chunk = blockIdx.x, tid = threadIdx.x;
    const u64* cb = cand + (size_t)b * 1024;

    for (int i = tid; i < PRE_K; i += 1024) {
        u64 key = cb[i];
        u32 a = ~(u32)key;
        float4 bx = boxes[(size_t)b * NA + a];
        float off = (float)labels[(size_t)b * NA + a] * 8192.0f;
        float x1 = bx.x + off, y1 = bx.y + off, x2 = bx.z + off, y2 = bx.w + off;
        sx1[i] = x1; sy1[i] = y1; sx2[i] = x2; sy2[i] = y2;
        float w = fmaxf(__fsub_rn(x2, x1), 0.0f);
        float h = fmaxf(__fsub_rn(y2, y1), 0.0f);
        sar[i] = __fmul_rn(w, h);
    }
    __syncthreads();

    for (int w0 = tid; w0 < 2000; w0 += 1024) {
        int il = w0 % 125, jw = w0 / 125;
        int i = chunk * 125 + il;
        float ax1 = sx1[i], ay1 = sy1[i], ax2 = sx2[i], ay2 = sy2[i], aar = sar[i];
        int jmax = min(64, PRE_K - jw * 64);
        u64 bits = 0;
        for (int jj = 0; jj < jmax; ++jj) {
            int j = jw * 64 + jj;
            float lx = fmaxf(ax1, sx1[j]), ly = fmaxf(ay1, sy1[j]);
            float rx = fminf(ax2, sx2[j]), ry = fminf(ay2, sy2[j]);
            float ww = fmaxf(__fsub_rn(rx, lx), 0.0f);
            float hh = fmaxf(__fsub_rn(ry, ly), 0.0f);
            float inter = __fmul_rn(ww, hh);
            float uni = __fsub_rn(__fadd_rn(aar, sar[j]), inter);
            float den = fmaxf(uni, 1e-6f);
            float iou = inter / den;
            if (iou > 0.65f) bits |= (1ull << jj);
        }
        mask[((size_t)b * PRE_K + i) * 16 + jw] = bits;
        if (jw == (i >> 6)) diag[(size_t)b * 1024 + i] = bits & ~(1ull << (i & 63));
    }
}

// ------------------------------------------------------------------
// Kernel 4: greedy-NMS scan.
// - diag (8 KB) in LDS: the only load on the cur critical path.
// - full rows streamed from global via depth-32 register pipeline
//   (compile-time slots; fully-unrolled 64-step chunks) feeding
//   sup |= row & m off the critical path (~500cyc covered by 32 steps).
// - chunk c refresh: cur = sup word c+1 via shfl64.
// - parallel epilogue: keep-words published to LDS, 1000 threads emit.
// ------------------------------------------------------------------
__global__ __launch_bounds__(1024) void k_nms(
    const u64* __restrict__ cand, const float4* __restrict__ boxes,
    const int* __restrict__ labels, const u64* __restrict__ mask,
    const u64* __restrict__ diag, float* __restrict__ out)
{
    __shared__ u64 sd[1024];
    __shared__ u64 pk[16];
    __shared__ u32 pref[16];
    __shared__ u32 sK;

    int b = blockIdx.x, tid = threadIdx.x, lane = tid & 63;
    const u64* cb = cand + (size_t)b * 1024;
    const u64* mb = mask + (size_t)b * PRE_K * 16;
    const u64* dg = diag + (size_t)b * 1024;

    sd[tid] = (tid < PRE_K) ? dg[tid] : 0ull;     // pad rows: never kept (m=0)
    __syncthreads();

    if (tid < 64) {
        int lw = lane & 15;                        // word mirrored by this lane (x4)
        // suppressed init = ~valid (pads i>=1000 suppressed)
        u64 sup = 0;
        for (int r = 0; r < 16; ++r) {
            int i = r * 64 + lane;
            u64 key = (i < PRE_K) ? cb[i] : 0ull;
            float sc = __uint_as_float((u32)(key >> 32));
            bool val = (i < PRE_K) && (sc > 0.25f);
            u64 mball = __ballot(val);
            if (lane == r) sup = ~mball;
        }
        u64 cur = shfl64(sup, 0);

        u64 rbuf[32];
        const char* mbc = (const char*)mb;
#pragma unroll
        for (int d = 0; d < 32; ++d)
            rbuf[d] = *(const u64*)(mbc + (size_t)d * 128 + lw * 8);

        for (int c = 0; c < 16; ++c) {
            u64 kc = 0;
            const char* rp = mbc + ((size_t)(c * 64 + 32)) * 128 + lw * 8;
            const u64* sdc = sd + c * 64;
#pragma unroll
            for (int u = 0; u < 64; ++u) {
                u64 rb = rbuf[u & 31];             // row c*64+u (loaded 32 steps ago)
                u64 sw = sdc[u];                   // diag word, self-bit clear
                u64 bitc = 1ull << u;              // compile-time constant
                u64 m = ((cur & bitc) == 0) ? ~0ull : 0ull;
                cur |= (sw & m);
                sup |= (rb & m);
                kc  |= (bitc & m);
                rbuf[u & 31] = *(const u64*)rp;    // prefetch row c*64+u+32
                rp += 128;
            }
            if (lane == 0) pk[c] = kc;
            if (c < 15) cur = shfl64(sup, c + 1);  // refresh from word c+1
        }

        // prefix of kept counts per chunk
        u64 kw = (lane < 16) ? pk[lane] : 0ull;
        int cnt = __popcll(kw);
        int pre = 0, K = 0;
        for (int w = 0; w < 16; ++w) {
            int cw = __shfl(cnt, w, 64);
            if (w < lane) pre += cw;
            K += cw;
        }
        if (lane < 16) pref[lane] = (u32)pre;
        if (lane == 0) sK = (u32)K;
    }
    __syncthreads();

    // parallel epilogue: one thread per candidate
    if (tid < PRE_K) {
        int c = tid >> 6, u = tid & 63;
        u64 kw = pk[c];
        u64 bitc = 1ull << u;
        int kb = __popcll(kw & (bitc - 1ull));
        bool kept = (kw & bitc) != 0ull;
        int K = (int)sK;
        int pc = (int)pref[c] + kb;                // kept with index < tid
        int row = kept ? pc : (K + (tid - pc));    // zero-score backfill, index order
        if (row < 100) {
            u64 key = cb[tid];
            u32 a = ~(u32)key;
            float4 bx = boxes[(size_t)b * NA + a];
            int lab = labels[(size_t)b * NA + a];
            float fsc = kept ? __uint_as_float((u32)(key >> 32)) : 0.0f;
            float* dr = out + (size_t)(b * 100 + row) * 5;
            dr[0] = bx.x; dr[1] = bx.y; dr[2] = bx.z; dr[3] = bx.w; dr[4] = fsc;
            out[(size_t)NB * 100 * 5 + b * 100 + row] = (float)lab;
        }
    }
}

extern "C" void kernel_launch(void* const* d_in, const int* in_sizes, int n_in,
                              void* d_out, int out_size, void* d_ws, size_t ws_size,
                              hipStream_t stream) {
    const float* cls0 = (const float*)d_in[0];
    const float* cls1 = (const float*)d_in[1];
    const float* cls2 = (const float*)d_in[2];
    const float* box0 = (const float*)d_in[3];
    const float* box1 = (const float*)d_in[4];
    const float* box2 = (const float*)d_in[5];
    float* out = (float*)d_out;

    char* w = (char*)d_ws;
    u64*    f_keys = (u64*)(w);
    float4* boxes  = (float4*)(w + 1075200);
    int*    labels = (int*)(w + 3225600);
    u64*    cand   = (u64*)(w + 3763200);
    u64*    mask   = (u64*)(w + 3894272);
    u64*    diag   = (u64*)(w + 5942272);

    k_decode<<<dim3(33, NB), 256, 0, stream>>>(cls0, cls1, cls2, box0, box1, box2,
                                               f_keys, boxes, labels);
    k_sort<<<NB, 1024, 0, stream>>>(f_keys, cand);
    k_iou<<<dim3(8, NB), 1024, 0, stream>>>(cand, boxes, labels, mask, diag);
    k_nms<<<NB, 1024, 0, stream>>>(cand, boxes, labels, mask, diag, out);
}

// Round 5
// 191.733 us; speedup vs baseline: 2.6429x; 2.6429x over previous
//
#include <hip/hip_runtime.h>
#include <math.h>
#include <stdint.h>

typedef unsigned long long u64;
typedef unsigned int u32;

#define NCLS 80
#define NA   8400
#define NB   16
#define PRE_K 1000

// ---------------- ws layout (bytes) ----------------
// f_keys : u64   [NB][NA]       @ 0         (1,075,200)
// boxes  : float4[NB][NA]       @ 1,075,200 (2,150,400)
// labels : int   [NB][NA]       @ 3,225,600 (  537,600)
// cand   : u64   [NB][1024]     @ 3,763,200 (  131,072)
// maskT  : u64   [NB][16][1024] @ 3,894,272 (2,097,152)  maskT[b][w][i] = IoU word w of row i
// total ~5.99 MB

__device__ inline u64 rfl64(u64 v) {
    u32 lo = __builtin_amdgcn_readfirstlane((u32)v);
    u32 hi = __builtin_amdgcn_readfirstlane((u32)(v >> 32));
    return ((u64)hi << 32) | lo;
}
__device__ inline u64 orx64(u64 v, int m) {
    u32 lo = (u32)__shfl_xor((int)(u32)v, m, 64);
    u32 hi = (u32)__shfl_xor((int)(u32)(v >> 32), m, 64);
    return v | (((u64)hi << 32) | lo);
}

// ------------------------------------------------------------------
// Kernel 1: per-anchor max/argmax over 80 classes, sigmoid score,
// box decode, sort-key emit.  (unchanged)
// ------------------------------------------------------------------
__global__ __launch_bounds__(256) void k_decode(
    const float* __restrict__ cls0, const float* __restrict__ cls1,
    const float* __restrict__ cls2, const float* __restrict__ box0,
    const float* __restrict__ box1, const float* __restrict__ box2,
    u64* __restrict__ f_keys, float4* __restrict__ boxes,
    int* __restrict__ labels)
{
    int a = blockIdx.x * blockDim.x + threadIdx.x;
    int b = blockIdx.y;
    if (a >= NA) return;

    const float* clsp; const float* boxp;
    int Wd, s, hw, HW;
    if (a < 6400)      { clsp = cls0; boxp = box0; Wd = 80; s = 8;  hw = a;        HW = 6400; }
    else if (a < 8000) { clsp = cls1; boxp = box1; Wd = 40; s = 16; hw = a - 6400; HW = 1600; }
    else               { clsp = cls2; boxp = box2; Wd = 20; s = 32; hw = a - 8000; HW = 400;  }

    const float* cp = clsp + (size_t)b * NCLS * HW + hw;
    float m = cp[0];
    int lab = 0;
#pragma unroll 8
    for (int c = 1; c < NCLS; ++c) {
        float v = cp[(size_t)c * HW];
        if (v > m) { m = v; lab = c; }   // strict > keeps first index on ties
    }
    double e = exp(-(double)m);
    float sc = (float)(1.0 / (1.0 + e));
    float sz = (sc > 0.25f) ? sc : 0.0f;
    f_keys[(size_t)b * NA + a] = ((u64)__float_as_uint(sz) << 32) | (u64)(~(u32)a);

    const float* bp = boxp + (size_t)b * 4 * HW + hw;
    float fs = (float)s;
    float d0 = bp[0] * fs, d1 = bp[HW] * fs, d2 = bp[2 * HW] * fs, d3 = bp[3 * HW] * fs;
    float px = (float)((hw % Wd) * s);
    float py = (float)((hw / Wd) * s);
    boxes[(size_t)b * NA + a] = make_float4(px - d0, py - d1, px + d2, py + d3);
    labels[(size_t)b * NA + a] = lab;
}

// ------------------------------------------------------------------
// Kernel 2: exact top-1000 via histogram selection + bitonic-2048.
// Fallback: full bitonic-8192 path (correct for any input). (unchanged)
// ------------------------------------------------------------------
__global__ __launch_bounds__(1024) void k_sort(
    const u64* __restrict__ f_keys, u64* __restrict__ cand)
{
    __shared__ u64 sh[8192];            // 64 KB; fast path aliases regions
    u32* H    = (u32*)sh;               // 4096 bins   -> sh[0..2047]
    u32* CS   = (u32*)(sh + 2048);      // 1024 sums   -> sh[2048..2559]
    u64* BUF  = sh + 4096;              // 2048 keys   -> sh[4096..6143]
    u32* MISC = (u32*)(sh + 6144);      // [0]=total [1]=B [2]=C [3]=cnt

    int b = blockIdx.x, tid = threadIdx.x, lane = tid & 63;
    const u64* fk = f_keys + (size_t)b * NA;
    u64* cb = cand + (size_t)b * 1024;

    for (int i = tid; i < 4096; i += 1024) H[i] = 0;
    if (tid == 0) { MISC[0] = 0; MISC[1] = 0; MISC[2] = 0xFFFFFFFFu; MISC[3] = 0; }
    __syncthreads();

    for (int i = tid; i < NA; i += 1024) {
        u32 sb = (u32)(fk[i] >> 32);
        if (sb) {
            int bin = (int)(sb >> 12) - 0x3E800;
            bin = max(0, min(bin, 4095));
            atomicAdd(&H[bin], 1u);
        }
    }
    __syncthreads();

    CS[tid] = H[4*tid] + H[4*tid+1] + H[4*tid+2] + H[4*tid+3];
    __syncthreads();

    if (tid < 64) {
        u32 g = 0;
        for (int j = 0; j < 16; ++j) g += CS[lane*16 + j];
        u32 S = g;
        for (int off = 1; off < 64; off <<= 1) {
            u32 x = __shfl_down(S, off, 64);
            if (lane + off < 64) S += x;          // suffix sum over lane chunks
        }
        if (lane == 0) MISC[0] = S;
        u32 Snext = S - g;
        if (S >= PRE_K && Snext < PRE_K) {        // unique crossing lane
            u32 accAbove = Snext;
            int tB = lane * 16;
            for (int j = 15; j >= 0; --j) {
                u32 c4 = CS[lane*16 + j];
                if (accAbove + c4 >= PRE_K) { tB = lane*16 + j; break; }
                accAbove += c4;
            }
            int B = 4 * tB; u32 Cv = 0;
            for (int k2 = 3; k2 >= 0; --k2) {
                u32 hc = H[4*tB + k2];
                if (accAbove + hc >= PRE_K) { B = 4*tB + k2; Cv = accAbove + hc; break; }
                accAbove += hc;
            }
            MISC[1] = (u32)B; MISC[2] = Cv;
        }
    }
    __syncthreads();
    u32 total = MISC[0], Bb = MISC[1], Cv = MISC[2];
    bool fb = (total < PRE_K) || (Cv > 2048);     // block-uniform

    if (!fb) {
        for (int i = tid; i < NA; i += 1024) {
            u64 key = fk[i];
            u32 sb = (u32)(key >> 32);
            if (sb) {
                int bin = (int)(sb >> 12) - 0x3E800;
                bin = max(0, min(bin, 4095));
                if ((u32)bin >= Bb) {
                    u32 p = atomicAdd(&MISC[3], 1u);
                    BUF[p] = key;
                }
            }
        }
        __syncthreads();
        for (int i = tid; i < 2048; i += 1024) if (i >= (int)Cv) BUF[i] = 0ull;
        __syncthreads();
        for (int k = 2; k <= 2048; k <<= 1) {
            for (int j = k >> 1; j > 0; j >>= 1) {
                int i = ((tid & ~(j-1)) << 1) | (tid & (j-1));
                int l = i | j;
                u64 x = BUF[i], y = BUF[l];
                bool sw = ((i & k) == 0) ? (x < y) : (x > y);
                if (sw) { BUF[i] = y; BUF[l] = x; }
                __syncthreads();
            }
        }
        if (tid < PRE_K) cb[tid] = BUF[tid];
    } else {
        __syncthreads();
        for (int i = tid; i < 8192; i += 1024) sh[i] = fk[i];
        __syncthreads();
        for (int k = 2; k <= 8192; k <<= 1) {
            for (int j = k >> 1; j > 0; j >>= 1) {
                for (int t = tid; t < 4096; t += 1024) {
                    int i = ((t & ~(j - 1)) << 1) | (t & (j - 1));
                    int l = i | j;
                    u64 x = sh[i], y = sh[l];
                    bool sw = ((i & k) == 0) ? (x < y) : (x > y);
                    if (sw) { sh[i] = y; sh[l] = x; }
                }
                __syncthreads();
            }
        }
        if (tid < 256) sh[7936 + tid] = (tid < 208) ? fk[8192 + tid] : 0ull;
        __syncthreads();
        for (int k = 2; k <= 256; k <<= 1) {
            for (int j = k >> 1; j > 0; j >>= 1) {
                for (int t = tid; t < 128; t += 1024) {
                    int i = ((t & ~(j - 1)) << 1) | (t & (j - 1));
                    int l = i | j;
                    u64 x = sh[7936 + i], y = sh[7936 + l];
                    bool sw = ((i & k) == 0) ? (x < y) : (x > y);
                    if (sw) { sh[7936 + i] = y; sh[7936 + l] = x; }
                }
                __syncthreads();
            }
        }
        if (tid < 1000) {
            u64 x = sh[tid];
            int lo = 0, hi = 256;
            while (lo < hi) { int mid = (lo + hi) >> 1; if (sh[7936 + mid] > x) lo = mid + 1; else hi = mid; }
            int r = tid + lo;
            if (r < PRE_K) cb[r] = x;
        }
        if (tid < 256) {
            u64 x = sh[7936 + tid];
            int lo = 0, hi = 1024;
            while (lo < hi) { int mid = (lo + hi) >> 1; if (sh[mid] > x) lo = mid + 1; else hi = mid; }
            int r = tid + lo;
            if (r < PRE_K) cb[r] = x;
        }
    }
}

// ------------------------------------------------------------------
// Kernel 3: IoU bitmask matrix, TRANSPOSED layout:
// maskT[b][w][i] = word w (candidates 64w..64w+63) of row i.
// Column w (all rows) is contiguous -> coalesced stream in k_nms.
// ------------------------------------------------------------------
__global__ __launch_bounds__(1024) void k_iou(
    const u64* __restrict__ cand, const float4* __restrict__ boxes,
    const int* __restrict__ labels, u64* __restrict__ maskT)
{
    __shared__ float sx1[1000], sy1[1000], sx2[1000], sy2[1000], sar[1000];
    int b = blockIdx.y, chunk = blockIdx.x, tid = threadIdx.x;
    const u64* cb = cand + (size_t)b * 1024;

    for (int i = tid; i < PRE_K; i += 1024) {
        u64 key = cb[i];
        u32 a = ~(u32)key;
        float4 bx = boxes[(size_t)b * NA + a];
        float off = (float)labels[(size_t)b * NA + a] * 8192.0f;
        float x1 = bx.x + off, y1 = bx.y + off, x2 = bx.z + off, y2 = bx.w + off;
        sx1[i] = x1; sy1[i] = y1; sx2[i] = x2; sy2[i] = y2;
        float w = fmaxf(__fsub_rn(x2, x1), 0.0f);
        float h = fmaxf(__fsub_rn(y2, y1), 0.0f);
        sar[i] = __fmul_rn(w, h);
    }
    __syncthreads();

    for (int w0 = tid; w0 < 2000; w0 += 1024) {
        int il = w0 % 125, jw = w0 / 125;
        int i = chunk * 125 + il;
        float ax1 = sx1[i], ay1 = sy1[i], ax2 = sx2[i], ay2 = sy2[i], aar = sar[i];
        int jmax = min(64, PRE_K - jw * 64);
        u64 bits = 0;
        for (int jj = 0; jj < jmax; ++jj) {
            int j = jw * 64 + jj;
            float lx = fmaxf(ax1, sx1[j]), ly = fmaxf(ay1, sy1[j]);
            float rx = fminf(ax2, sx2[j]), ry = fminf(ay2, sy2[j]);
            float ww = fmaxf(__fsub_rn(rx, lx), 0.0f);
            float hh = fmaxf(__fsub_rn(ry, ly), 0.0f);
            float inter = __fmul_rn(ww, hh);
            float uni = __fsub_rn(__fadd_rn(aar, sar[j]), inter);
            float den = fmaxf(uni, 1e-6f);
            float iou = inter / den;
            if (iou > 0.65f) bits |= (1ull << jj);
        }
        maskT[((size_t)b * 16 + jw) * 1024 + i] = bits;
    }
}

// ------------------------------------------------------------------
// Kernel 4: greedy-NMS, single wave per batch, 64 threads.
// R4 post-mortem: 1024-thread block capped VGPRs at 64 -> pipeline
// spilled to scratch (WRITE_SIZE 994 KB). Now: block=64, VGPR budget
// ~512; column-lazy scan on the transposed mask:
//  - col[16]: column c (word c of rows k*64+lane), coalesced prefetch
//    one chunk ahead into registers.
//  - cur for chunk c = OR of kept rows' word c (pk-masked terms k<c,
//    butterfly OR-reduce).
//  - within-chunk: wave-uniform find-first-set loop, ~6 scalar ops per
//    KEPT box (readlane pulls row u's word from lane u).
//  - parallel 16-iter epilogue on the same wave.
// ------------------------------------------------------------------
__global__ __launch_bounds__(64, 1) void k_nms(
    const u64* __restrict__ cand, const float4* __restrict__ boxes,
    const int* __restrict__ labels, const u64* __restrict__ maskT,
    float* __restrict__ out)
{
    int b = blockIdx.x, lane = threadIdx.x;
    const u64* cb = cand + (size_t)b * 1024;
    const u64* mt = maskT + (size_t)b * 16 * 1024;
    u64 lanebit = 1ull << lane;

    // valid masks per chunk (uniform): score bits nonzero iff sc>0.25
    u64 pv[16];
#pragma unroll
    for (int k = 0; k < 16; ++k) {
        int i = k * 64 + lane;
        u64 key = (i < PRE_K) ? cb[i] : 0ull;
        bool val = (i < PRE_K) && ((u32)(key >> 32) != 0u);
        pv[k] = __ballot(val);
    }

    u64 col[16], nxt[16], pk[16];
#pragma unroll
    for (int k = 0; k < 16; ++k) col[k] = mt[k * 64 + lane];   // column 0

#define CHUNK(c)                                                           \
    {                                                                      \
        if ((c) < 15) {                                                    \
            _Pragma("unroll")                                              \
            for (int k = 0; k < 16; ++k)                                   \
                nxt[k] = mt[((c) + 1) * 1024 + k * 64 + lane];             \
        }                                                                  \
        u64 cur = 0;                                                       \
        _Pragma("unroll")                                                  \
        for (int k = 0; k < (c); ++k)                                      \
            cur |= (pk[k] & lanebit) ? col[k] : 0ull;                      \
        if ((c) > 0) {                                                     \
            _Pragma("unroll")                                              \
            for (int m = 1; m < 64; m <<= 1) cur = orx64(cur, m);          \
        }                                                                  \
        u64 active = rfl64(pv[(c)] & ~cur);                                \
        u32 rlo = (u32)col[(c)], rhi = (u32)(col[(c)] >> 32);              \
        u64 kc = 0;                                                        \
        while (active) {                                                   \
            int u = __builtin_ctzll(active);                               \
            u64 bit = 1ull << u;                                           \
            u64 row = ((u64)(u32)__builtin_amdgcn_readlane((int)rhi, u) << 32) \
                      | (u32)__builtin_amdgcn_readlane((int)rlo, u);       \
            kc |= bit;                                                     \
            active &= ~(row | bit);                                        \
        }                                                                  \
        pk[(c)] = kc;                                                      \
        if ((c) < 15) {                                                    \
            _Pragma("unroll")                                              \
            for (int k = 0; k < 16; ++k) col[k] = nxt[k];                  \
        }                                                                  \
    }

    CHUNK(0)  CHUNK(1)  CHUNK(2)  CHUNK(3)
    CHUNK(4)  CHUNK(5)  CHUNK(6)  CHUNK(7)
    CHUNK(8)  CHUNK(9)  CHUNK(10) CHUNK(11)
    CHUNK(12) CHUNK(13) CHUNK(14) CHUNK(15)
#undef CHUNK

    // prefix of kept counts per chunk (uniform scalars)
    int pref16[16];
    int acc = 0;
#pragma unroll
    for (int k = 0; k < 16; ++k) { pref16[k] = acc; acc += __popcll(pk[k]); }
    int K = acc;

    // parallel epilogue: 16 iterations x 64 lanes = 1024 candidates
#pragma unroll
    for (int t = 0; t < 16; ++t) {
        int i = t * 64 + lane;
        if (t < 15 || lane < (PRE_K - 15 * 64)) {
            u64 kw = pk[t];
            int kb = __popcll(kw & (lanebit - 1ull));
            bool kept = (kw & lanebit) != 0ull;
            int pc = pref16[t] + kb;                 // kept with index < i
            int row = kept ? pc : (K + (i - pc));    // zero-score backfill, index order
            if (row < 100) {
                u64 key = cb[i];
                u32 a = ~(u32)key;
                float4 bx = boxes[(size_t)b * NA + a];
                int lab = labels[(size_t)b * NA + a];
                float fsc = kept ? __uint_as_float((u32)(key >> 32)) : 0.0f;
                float* dr = out + (size_t)(b * 100 + row) * 5;
                dr[0] = bx.x; dr[1] = bx.y; dr[2] = bx.z; dr[3] = bx.w; dr[4] = fsc;
                out[(size_t)NB * 100 * 5 + b * 100 + row] = (float)lab;
            }
        }
    }
}

extern "C" void kernel_launch(void* const* d_in, const int* in_sizes, int n_in,
                              void* d_out, int out_size, void* d_ws, size_t ws_size,
                              hipStream_t stream) {
    const float* cls0 = (const float*)d_in[0];
    const float* cls1 = (const float*)d_in[1];
    const float* cls2 = (const float*)d_in[2];
    const float* box0 = (const float*)d_in[3];
    const float* box1 = (const float*)d_in[4];
    const float* box2 = (const float*)d_in[5];
    float* out = (float*)d_out;

    char* w = (char*)d_ws;
    u64*    f_keys = (u64*)(w);
    float4* boxes  = (float4*)(w + 1075200);
    int*    labels = (int*)(w + 3225600);
    u64*    cand   = (u64*)(w + 3763200);
    u64*    maskT  = (u64*)(w + 3894272);

    k_decode<<<dim3(33, NB), 256, 0, stream>>>(cls0, cls1, cls2, box0, box1, box2,
                                               f_keys, boxes, labels);
    k_sort<<<NB, 1024, 0, stream>>>(f_keys, cand);
    k_iou<<<dim3(8, NB), 1024, 0, stream>>>(cand, boxes, labels, maskT);
    k_nms<<<NB, 64, 0, stream>>>(cand, boxes, labels, maskT, out);
}

// Round 6
// 155.944 us; speedup vs baseline: 3.2494x; 1.2295x over previous
//
#include <hip/hip_runtime.h>
#include <math.h>
#include <stdint.h>

typedef unsigned long long u64;
typedef unsigned int u32;

#define NCLS 80
#define NA   8400
#define NB   16
#define PRE_K 1000

// ---------------- ws layout (bytes) ----------------
// f_keys : u64   [NB][NA]       @ 0         (1,075,200)
// boxes  : float4[NB][NA]       @ 1,075,200 (2,150,400)
// labels : int   [NB][NA]       @ 3,225,600 (  537,600)
// cand   : u64   [NB][1024]     @ 3,763,200 (  131,072)
// mask   : u64   [NB][1000][16] @ 3,894,272 (2,048,000)  row-major IoU bitmask
// total ~5.94 MB

// ------------------------------------------------------------------
// Kernel 1: per-anchor max/argmax over 80 classes, sigmoid score,
// box decode, sort-key emit.  (unchanged)
// ------------------------------------------------------------------
__global__ __launch_bounds__(256) void k_decode(
    const float* __restrict__ cls0, const float* __restrict__ cls1,
    const float* __restrict__ cls2, const float* __restrict__ box0,
    const float* __restrict__ box1, const float* __restrict__ box2,
    u64* __restrict__ f_keys, float4* __restrict__ boxes,
    int* __restrict__ labels)
{
    int a = blockIdx.x * blockDim.x + threadIdx.x;
    int b = blockIdx.y;
    if (a >= NA) return;

    const float* clsp; const float* boxp;
    int Wd, s, hw, HW;
    if (a < 6400)      { clsp = cls0; boxp = box0; Wd = 80; s = 8;  hw = a;        HW = 6400; }
    else if (a < 8000) { clsp = cls1; boxp = box1; Wd = 40; s = 16; hw = a - 6400; HW = 1600; }
    else               { clsp = cls2; boxp = box2; Wd = 20; s = 32; hw = a - 8000; HW = 400;  }

    const float* cp = clsp + (size_t)b * NCLS * HW + hw;
    float m = cp[0];
    int lab = 0;
#pragma unroll 8
    for (int c = 1; c < NCLS; ++c) {
        float v = cp[(size_t)c * HW];
        if (v > m) { m = v; lab = c; }   // strict > keeps first index on ties
    }
    double e = exp(-(double)m);
    float sc = (float)(1.0 / (1.0 + e));
    float sz = (sc > 0.25f) ? sc : 0.0f;
    f_keys[(size_t)b * NA + a] = ((u64)__float_as_uint(sz) << 32) | (u64)(~(u32)a);

    const float* bp = boxp + (size_t)b * 4 * HW + hw;
    float fs = (float)s;
    float d0 = bp[0] * fs, d1 = bp[HW] * fs, d2 = bp[2 * HW] * fs, d3 = bp[3 * HW] * fs;
    float px = (float)((hw % Wd) * s);
    float py = (float)((hw / Wd) * s);
    boxes[(size_t)b * NA + a] = make_float4(px - d0, py - d1, px + d2, py + d3);
    labels[(size_t)b * NA + a] = lab;
}

// ------------------------------------------------------------------
// Kernel 2: exact top-1000 via histogram selection + bitonic-2048.
// Fallback: full bitonic-8192 path (correct for any input). (unchanged)
// ------------------------------------------------------------------
__global__ __launch_bounds__(1024) void k_sort(
    const u64* __restrict__ f_keys, u64* __restrict__ cand)
{
    __shared__ u64 sh[8192];            // 64 KB; fast path aliases regions
    u32* H    = (u32*)sh;               // 4096 bins   -> sh[0..2047]
    u32* CS   = (u32*)(sh + 2048);      // 1024 sums   -> sh[2048..2559]
    u64* BUF  = sh + 4096;              // 2048 keys   -> sh[4096..6143]
    u32* MISC = (u32*)(sh + 6144);      // [0]=total [1]=B [2]=C [3]=cnt

    int b = blockIdx.x, tid = threadIdx.x, lane = tid & 63;
    const u64* fk = f_keys + (size_t)b * NA;
    u64* cb = cand + (size_t)b * 1024;

    for (int i = tid; i < 4096; i += 1024) H[i] = 0;
    if (tid == 0) { MISC[0] = 0; MISC[1] = 0; MISC[2] = 0xFFFFFFFFu; MISC[3] = 0; }
    __syncthreads();

    for (int i = tid; i < NA; i += 1024) {
        u32 sb = (u32)(fk[i] >> 32);
        if (sb) {
            int bin = (int)(sb >> 12) - 0x3E800;
            bin = max(0, min(bin, 4095));
            atomicAdd(&H[bin], 1u);
        }
    }
    __syncthreads();

    CS[tid] = H[4*tid] + H[4*tid+1] + H[4*tid+2] + H[4*tid+3];
    __syncthreads();

    if (tid < 64) {
        u32 g = 0;
        for (int j = 0; j < 16; ++j) g += CS[lane*16 + j];
        u32 S = g;
        for (int off = 1; off < 64; off <<= 1) {
            u32 x = __shfl_down(S, off, 64);
            if (lane + off < 64) S += x;          // suffix sum over lane chunks
        }
        if (lane == 0) MISC[0] = S;
        u32 Snext = S - g;
        if (S >= PRE_K && Snext < PRE_K) {        // unique crossing lane
            u32 accAbove = Snext;
            int tB = lane * 16;
            for (int j = 15; j >= 0; --j) {
                u32 c4 = CS[lane*16 + j];
                if (accAbove + c4 >= PRE_K) { tB = lane*16 + j; break; }
                accAbove += c4;
            }
            int B = 4 * tB; u32 Cv = 0;
            for (int k2 = 3; k2 >= 0; --k2) {
                u32 hc = H[4*tB + k2];
                if (accAbove + hc >= PRE_K) { B = 4*tB + k2; Cv = accAbove + hc; break; }
                accAbove += hc;
            }
            MISC[1] = (u32)B; MISC[2] = Cv;
        }
    }
    __syncthreads();
    u32 total = MISC[0], Bb = MISC[1], Cv = MISC[2];
    bool fb = (total < PRE_K) || (Cv > 2048);     // block-uniform

    if (!fb) {
        for (int i = tid; i < NA; i += 1024) {
            u64 key = fk[i];
            u32 sb = (u32)(key >> 32);
            if (sb) {
                int bin = (int)(sb >> 12) - 0x3E800;
                bin = max(0, min(bin, 4095));
                if ((u32)bin >= Bb) {
                    u32 p = atomicAdd(&MISC[3], 1u);
                    BUF[p] = key;
                }
            }
        }
        __syncthreads();
        for (int i = tid; i < 2048; i += 1024) if (i >= (int)Cv) BUF[i] = 0ull;
        __syncthreads();
        for (int k = 2; k <= 2048; k <<= 1) {
            for (int j = k >> 1; j > 0; j >>= 1) {
                int i = ((tid & ~(j-1)) << 1) | (tid & (j-1));
                int l = i | j;
                u64 x = BUF[i], y = BUF[l];
                bool sw = ((i & k) == 0) ? (x < y) : (x > y);
                if (sw) { BUF[i] = y; BUF[l] = x; }
                __syncthreads();
            }
        }
        if (tid < PRE_K) cb[tid] = BUF[tid];
    } else {
        __syncthreads();
        for (int i = tid; i < 8192; i += 1024) sh[i] = fk[i];
        __syncthreads();
        for (int k = 2; k <= 8192; k <<= 1) {
            for (int j = k >> 1; j > 0; j >>= 1) {
                for (int t = tid; t < 4096; t += 1024) {
                    int i = ((t & ~(j - 1)) << 1) | (t & (j - 1));
                    int l = i | j;
                    u64 x = sh[i], y = sh[l];
                    bool sw = ((i & k) == 0) ? (x < y) : (x > y);
                    if (sw) { sh[i] = y; sh[l] = x; }
                }
                __syncthreads();
            }
        }
        if (tid < 256) sh[7936 + tid] = (tid < 208) ? fk[8192 + tid] : 0ull;
        __syncthreads();
        for (int k = 2; k <= 256; k <<= 1) {
            for (int j = k >> 1; j > 0; j >>= 1) {
                for (int t = tid; t < 128; t += 1024) {
                    int i = ((t & ~(j - 1)) << 1) | (t & (j - 1));
                    int l = i | j;
                    u64 x = sh[7936 + i], y = sh[7936 + l];
                    bool sw = ((i & k) == 0) ? (x < y) : (x > y);
                    if (sw) { sh[7936 + i] = y; sh[7936 + l] = x; }
                }
                __syncthreads();
            }
        }
        if (tid < 1000) {
            u64 x = sh[tid];
            int lo = 0, hi = 256;
            while (lo < hi) { int mid = (lo + hi) >> 1; if (sh[7936 + mid] > x) lo = mid + 1; else hi = mid; }
            int r = tid + lo;
            if (r < PRE_K) cb[r] = x;
        }
        if (tid < 256) {
            u64 x = sh[7936 + tid];
            int lo = 0, hi = 1024;
            while (lo < hi) { int mid = (lo + hi) >> 1; if (sh[mid] > x) lo = mid + 1; else hi = mid; }
            int r = tid + lo;
            if (r < PRE_K) cb[r] = x;
        }
    }
}

// ------------------------------------------------------------------
// Kernel 3: IoU bitmask matrix, row-major:
// mask[b][i][w] bit jj  <=>  iou(cand_i, cand_{64w+jj}) > 0.65
// (M is symmetric; k_nms uses rows as columns.)
// ------------------------------------------------------------------
__global__ __launch_bounds__(1024) void k_iou(
    const u64* __restrict__ cand, const float4* __restrict__ boxes,
    const int* __restrict__ labels, u64* __restrict__ mask)
{
    __shared__ float sx1[1000], sy1[1000], sx2[1000], sy2[1000], sar[1000];
    int b = blockIdx.y, chunk = blockIdx.x, tid = threadIdx.x;
    const u64* cb = cand + (size_t)b * 1024;

    for (int i = tid; i < PRE_K; i += 1024) {
        u64 key = cb[i];
        u32 a = ~(u32)key;
        float4 bx = boxes[(size_t)b * NA + a];
        float off = (float)labels[(size_t)b * NA + a] * 8192.0f;
        float x1 = bx.x + off, y1 = bx.y + off, x2 = bx.z + off, y2 = bx.w + off;
        sx1[i] = x1; sy1[i] = y1; sx2[i] = x2; sy2[i] = y2;
        float w = fmaxf(__fsub_rn(x2, x1), 0.0f);
        float h = fmaxf(__fsub_rn(y2, y1), 0.0f);
        sar[i] = __fmul_rn(w, h);
    }
    __syncthreads();

    for (int w0 = tid; w0 < 2000; w0 += 1024) {
        int il = w0 % 125, jw = w0 / 125;
        int i = chunk * 125 + il;
        float ax1 = sx1[i], ay1 = sy1[i], ax2 = sx2[i], ay2 = sy2[i], aar = sar[i];
        int jmax = min(64, PRE_K - jw * 64);
        u64 bits = 0;
        for (int jj = 0; jj < jmax; ++jj) {
            int j = jw * 64 + jj;
            float lx = fmaxf(ax1, sx1[j]), ly = fmaxf(ay1, sy1[j]);
            float rx = fminf(ax2, sx2[j]), ry = fminf(ay2, sy2[j]);
            float ww = fmaxf(__fsub_rn(rx, lx), 0.0f);
            float hh = fmaxf(__fsub_rn(ry, ly), 0.0f);
            float inter = __fmul_rn(ww, hh);
            float uni = __fsub_rn(__fadd_rn(aar, sar[j]), inter);
            float den = fmaxf(uni, 1e-6f);
            float iou = inter / den;
            if (iou > 0.65f) bits |= (1ull << jj);
        }
        mask[((size_t)b * PRE_K + i) * 16 + jw] = bits;
    }
}

// ------------------------------------------------------------------
// Kernel 4: greedy NMS as a PARALLEL FIXPOINT (Jacobi) iteration.
// keep_i = valid_i & !OR_{j<i}(keep_j & M[j][i]) is strictly lower-
// triangular -> unique fixpoint = greedy answer; synchronous iteration
// pins candidate i by iteration i (<=1000 guaranteed; ~3-8 expected on
// random data). Thread i holds its (j<i)-masked row in 32 VGPRs; the
// 16-word keep mask K lives in LDS (broadcast reads). No serial scan.
// R5 post-mortem: serial single-wave scan floored at ~50us regardless
// of per-step tuning; this removes the serial structure entirely.
// ------------------------------------------------------------------
__global__ __launch_bounds__(1024, 1) void k_nms(
    const u64* __restrict__ cand, const float4* __restrict__ boxes,
    const int* __restrict__ labels, const u64* __restrict__ mask,
    float* __restrict__ out)
{
    __shared__ u64 Ksh[16];
    __shared__ int chg;

    int b = blockIdx.x, tid = threadIdx.x, lane = tid & 63, wv = tid >> 6;
    const u64* cb = cand + (size_t)b * 1024;
    const u64* mb = mask + (size_t)b * PRE_K * 16;

    bool inr = tid < PRE_K;
    u64 key = inr ? cb[tid] : 0ull;
    bool valid = inr && ((u32)(key >> 32) != 0u);   // score>0.25 iff bits nonzero

    u64 low = (1ull << (tid & 63)) - 1ull;          // lane 0 -> 0

    // row i, pre-masked to j<i (self-bit excluded by `low` at k==wv)
    u64 rowm[16];
#pragma unroll
    for (int k = 0; k < 16; ++k) {
        u64 r = inr ? mb[(size_t)tid * 16 + k] : 0ull;
        u64 lt = (k < wv) ? ~0ull : ((k == wv) ? low : 0ull);
        rowm[k] = r & lt;
    }

    // K^0 = valid
    u64 v0 = __ballot(valid);
    if (lane == 0) Ksh[wv] = v0;
    __syncthreads();

    for (int it = 0; it < PRE_K; ++it) {
        u64 acc = 0;
#pragma unroll
        for (int k = 0; k < 16; ++k) acc |= rowm[k] & Ksh[k];
        bool kept = valid && (acc == 0ull);
        u64 nk = __ballot(kept);
        u64 kold = Ksh[wv];                         // uniform per wave
        __syncthreads();                            // reads of Ksh done
        if (tid == 0) chg = 0;
        __syncthreads();
        if (lane == 0) { if (nk != kold) chg = 1; Ksh[wv] = nk; }
        __syncthreads();
        if (chg == 0) break;                        // K^{n+1}==K^n -> fixpoint
    }

    // epilogue: rank kept (by index) then zero-score backfill (by index)
    u64 kf = Ksh[wv];
    int pc = 0, Kt = 0;
#pragma unroll
    for (int k = 0; k < 16; ++k) {
        u64 kk = Ksh[k];
        u64 lt = (k < wv) ? ~0ull : ((k == wv) ? low : 0ull);
        pc += __popcll(kk & lt);
        Kt += __popcll(kk);
    }
    if (inr) {
        bool kept = (kf >> (tid & 63)) & 1ull;
        int row = kept ? pc : (Kt + (tid - pc));
        if (row < 100) {
            u32 a = ~(u32)key;
            float4 bx = boxes[(size_t)b * NA + a];
            int lab = labels[(size_t)b * NA + a];
            float fsc = kept ? __uint_as_float((u32)(key >> 32)) : 0.0f;
            float* dr = out + (size_t)(b * 100 + row) * 5;
            dr[0] = bx.x; dr[1] = bx.y; dr[2] = bx.z; dr[3] = bx.w; dr[4] = fsc;
            out[(size_t)NB * 100 * 5 + b * 100 + row] = (float)lab;
        }
    }
}

extern "C" void kernel_launch(void* const* d_in, const int* in_sizes, int n_in,
                              void* d_out, int out_size, void* d_ws, size_t ws_size,
                              hipStream_t stream) {
    const float* cls0 = (const float*)d_in[0];
    const float* cls1 = (const float*)d_in[1];
    const float* cls2 = (const float*)d_in[2];
    const float* box0 = (const float*)d_in[3];
    const float* box1 = (const float*)d_in[4];
    const float* box2 = (const float*)d_in[5];
    float* out = (float*)d_out;

    char* w = (char*)d_ws;
    u64*    f_keys = (u64*)(w);
    float4* boxes  = (float4*)(w + 1075200);
    int*    labels = (int*)(w + 3225600);
    u64*    cand   = (u64*)(w + 3763200);
    u64*    mask   = (u64*)(w + 3894272);

    k_decode<<<dim3(33, NB), 256, 0, stream>>>(cls0, cls1, cls2, box0, box1, box2,
                                               f_keys, boxes, labels);
    k_sort<<<NB, 1024, 0, stream>>>(f_keys, cand);
    k_iou<<<dim3(8, NB), 1024, 0, stream>>>(cand, boxes, labels, mask);
    k_nms<<<NB, 1024, 0, stream>>>(cand, boxes, labels, mask, out);
}